// Round 7
// baseline (439.156 us; speedup 1.0000x reference)
//
#include <hip/hip_runtime.h>
#include <hip/hip_bf16.h>
#include <cstdint>
#include <cstddef>

// MultiScaleQuantizer: z (256,32,16,16) fp32, embed (4096,32) fp32.
// Outputs concat (fp32): f_hat (2097152), idx@pn=1..16 (87296), loss (1).
//
// r23: codes-stationary scan. r16-r22 showed duration ~ 1/occupancy with
// pipe cuts (LDS conflicts halved, VALU cut) not helping: the scan was
// stall-bound on its own dependence structure (stage->barrier->ds_read
// latency) at ~3 blocks/CU. r23 deletes that structure: each wave holds
// 128 CODES in registers as the FIRST MFMA operand (8 bf16x8 frags + 8
// f32x4 cin of se/2, loaded once), and streams 16-point groups as the
// SECOND operand (one coalesced 16B global load each). Per m89 layout,
// D row m=(quad*4+r)=code, col n=point: per-point min is a per-lane
// fmin-chain + 2 cross-quad shuffles; phaseB threshold is a per-lane
// scalar thrv=decf(smin[point])+MARGIN. Hot loops have ZERO ds_read/
// ds_write and ZERO barriers; 8 independent MFMAs per load hide latency.
// Semantics identical to passing r16/r22: bf16 s-metric for candidate
// selection only, global-min thresholds, MARGIN=1.0, exact-fp32
// ascending-c rescue + atomicMin(key) -> identical winner and tie-break.

#define B_   256
#define V_   4096
#define NTOT 2097152   // 256*32*16*16
#define CAP  1024      // candidate list capacity per block (u64 entries)
#define MARGIN_ 1.0f

using bf16x8 = __attribute__((ext_vector_type(8))) short;
using f32x4  = __attribute__((ext_vector_type(4))) float;

__device__ inline short f2bf(float f) {
  __hip_bfloat16 h = __float2bfloat16(f);
  return *reinterpret_cast<short*>(&h);
}
__device__ inline unsigned encf(float f) {        // monotone fp32 -> u32
  unsigned u = __float_as_uint(f);
  return (u & 0x80000000u) ? ~u : (u | 0x80000000u);
}
__device__ inline float decf(unsigned u) {
  unsigned b = (u & 0x80000000u) ? (u ^ 0x80000000u) : ~u;
  return __uint_as_float(b);
}
__device__ inline int keyidx(unsigned long long k) {  // decode + clamp (safety)
  int i = (int)(unsigned)(k & 0xffffffffull);
  return min(max(i, 0), V_ - 1);
}
__device__ inline float min3f(float a, float b, float c) {
  float d;
  asm("v_min3_f32 %0, %1, %2, %3" : "=v"(d) : "v"(a), "v"(b), "v"(c));
  return d;
}

// ---- setup: f_rest=z, zrow/zrowb@pn1, ebf, se/sehalf, tables, inits ----
// block = one (b,c) plane; blockIdx.x = b*32+c
__global__ __launch_bounds__(256) void setup_kernel(
    const float* __restrict__ z, const float* __restrict__ embed,
    float* __restrict__ f_rest, float* __restrict__ zrow,
    short* __restrict__ zrowb, short* __restrict__ ebf,
    float* __restrict__ se, float* __restrict__ sehalf,
    float* __restrict__ tables, float* __restrict__ loss_slots,
    unsigned long long* __restrict__ keys0, unsigned int* __restrict__ smin0)
{
  const int tid = threadIdx.x;
  const int t = blockIdx.x * 256 + tid;
  float v = z[t];
  f_rest[t] = v;

  __shared__ float sm[256];
  sm[tid] = v;
  __syncthreads();
  if (tid == 0) {
    float s = 0.f;
    for (int i = 0; i < 256; ++i) s += sm[i];   // ref's linear i,j order
    int c = blockIdx.x & 31, b = blockIdx.x >> 5;
    float val = s * (1.0f / 256.0f);
    zrow[(size_t)b * 32 + c] = val;             // row-major [n][32]
    zrowb[(size_t)b * 32 + c] = f2bf(-val);     // negated bf16, 2nd operand
  }

  if (blockIdx.x < 16) {                        // se/sehalf + ebf: 16*256 codes
    int code = blockIdx.x * 256 + tid;
    float s = 0.f;
#pragma unroll
    for (int c = 0; c < 32; ++c) {
      float e = embed[(size_t)code * 32 + c];
      ebf[(size_t)code * 32 + c] = f2bf(e);
      s += e * e;                                // sequential like ref
    }
    se[code] = s;
    sehalf[code] = 0.5f * s;                     // *0.5 exact
  } else if (blockIdx.x == 16) {
    if (tid < 64) {
      int pn_i = tid >> 4;          // 0..3 -> pn = 1,2,4,8
      int o    = tid & 15;
      int pn   = 1 << pn_i;
      double scale = (double)pn / 16.0;
      double x  = (o + 0.5) * scale - 0.5;
      double x0 = floor(x);
      double tf = x - x0;
      float row[8];
#pragma unroll
      for (int h = 0; h < 8; ++h) row[h] = 0.f;
      const double A = -0.75;
#pragma unroll
      for (int off = -1; off <= 2; ++off) {
        double s = fabs(tf - (double)off);
        double cub;
        if (s <= 1.0)      cub = ((A + 2.0) * s - (A + 3.0)) * s * s + 1.0;
        else if (s < 2.0)  cub = (((s - 5.0) * s + 8.0) * s - 4.0) * A;
        else               cub = 0.0;
        int idx = (int)x0 + off;
        idx = min(max(idx, 0), pn - 1);
        row[idx] = (float)((double)row[idx] + cub);  // numpy f32 += f64
      }
#pragma unroll
      for (int h = 0; h < 8; ++h) tables[pn_i * 128 + o * 8 + h] = row[h];
    }
  } else if (blockIdx.x == 17) {
    keys0[tid] = ~0ull;                          // pn=1: N=256
    smin0[tid] = 0xFFFFFFFFu;
  } else if (blockIdx.x >= 20 && blockIdx.x < 60) {
    loss_slots[(blockIdx.x - 20) * 256 + tid] = 0.f;   // 40*256 = 10240 zeros
  }
}

// ------- phase A: codes-in-regs scan -> per-point global min (encf) -------
// block = 4 waves x 128 codes = 512-code slice; grid (N/(16*giter), 8).
// Each wave streams giter 16-point groups over its 128 codes.
__global__ __launch_bounds__(256) void vq_phaseA_kernel(
    const short* __restrict__ zrowb, const short* __restrict__ ebf,
    const float* __restrict__ sehalf, unsigned int* __restrict__ smin,
    int giter)
{
  const int tid = threadIdx.x;
  const int lane = tid & 63, wave = tid >> 6;
  const int col = lane & 15, quad = lane >> 4;
  const int cb = blockIdx.y * 512 + wave * 128;      // this wave's code base
  const int pb0 = blockIdx.x * (giter * 16);         // block's point base

  // code frags (1st operand): lane holds code (cb+f*16+col), k=quad*8..+7
  bf16x8 cf[8];
  f32x4  cin[8];   // cin[f][r] = se[cb+f*16+quad*4+r]/2  (D's m index)
#pragma unroll
  for (int f = 0; f < 8; ++f) {
    cf[f]  = *(const bf16x8*)(ebf + (size_t)(cb + f * 16 + col) * 32 + quad * 8);
    cin[f] = *(const f32x4*)(sehalf + cb + f * 16 + quad * 4);
  }

  for (int g = 0; g < giter; ++g) {
    const int pb = pb0 + g * 16;
    // point frag (2nd operand): lane holds point (pb+col), k=quad*8..+7
    bf16x8 pf = *(const bf16x8*)(zrowb + (size_t)(pb + col) * 32 + quad * 8);
    float m = 3.4e38f;
#pragma unroll
    for (int f = 0; f < 8; ++f) {
      f32x4 d = __builtin_amdgcn_mfma_f32_16x16x32_bf16(cf[f], pf, cin[f], 0, 0, 0);
      m = fminf(m, fminf(fminf(d[0], d[1]), fminf(d[2], d[3])));
    }
    // lane holds min over its 32 codes for point (pb+col); reduce over quads
    m = fminf(m, __shfl_xor(m, 16, 64));
    m = fminf(m, __shfl_xor(m, 32, 64));
    if (quad == 0)
      atomicMin(&smin[pb + col], encf(m));
  }
}

// -------- phase B: codes-in-regs re-scan; candidates -> batch rescue --------
__global__ __launch_bounds__(256) void vq_phaseB_kernel(
    const short* __restrict__ zrowb, const short* __restrict__ ebf,
    const float* __restrict__ sehalf, const unsigned int* __restrict__ smin,
    const float* __restrict__ zrow, const float* __restrict__ embed,
    const float* __restrict__ se, unsigned long long* __restrict__ keys,
    int giter, int nmax)
{
  __shared__ unsigned long long clist[CAP];
  __shared__ int ccnt;

  const int tid = threadIdx.x;
  const int lane = tid & 63, wave = tid >> 6;
  const int col = lane & 15, quad = lane >> 4;
  const int cb = blockIdx.y * 512 + wave * 128;
  const int pb0 = blockIdx.x * (giter * 16);

  if (tid == 0) ccnt = 0;
  __syncthreads();

  bf16x8 cf[8];
  f32x4  cin[8];
#pragma unroll
  for (int f = 0; f < 8; ++f) {
    cf[f]  = *(const bf16x8*)(ebf + (size_t)(cb + f * 16 + col) * 32 + quad * 8);
    cin[f] = *(const f32x4*)(sehalf + cb + f * 16 + quad * 4);
  }

  for (int g = 0; g < giter; ++g) {
    const int pb = pb0 + g * 16;
    const int n = pb + col;                       // this lane's point
    bf16x8 pf = *(const bf16x8*)(zrowb + (size_t)n * 32 + quad * 8);
    float thrv = decf(smin[n]) + MARGIN_;         // per-point threshold
    f32x4 dv[8];
    float m = 3.4e38f;
#pragma unroll
    for (int f = 0; f < 8; ++f) {
      dv[f] = __builtin_amdgcn_mfma_f32_16x16x32_bf16(cf[f], pf, cin[f], 0, 0, 0);
      m = fminf(m, fminf(fminf(dv[f][0], dv[f][1]), fminf(dv[f][2], dv[f][3])));
    }
    if (m <= thrv) {                              // per-lane gate (exact)
#pragma unroll
      for (int f = 0; f < 8; ++f) {
#pragma unroll
        for (int r = 0; r < 4; ++r) {
          if (dv[f][r] <= thrv) {
            int v = cb + f * 16 + quad * 4 + r;
            int slot = atomicAdd(&ccnt, 1);       // LDS atomic
            if (slot < CAP) {
              clist[slot] =
                  ((unsigned long long)(unsigned)n << 32) | (unsigned)v;
            } else {
              // overflow fallback: exact inline (ascending-c fp order)
              const float* zp = zrow + (size_t)n * 32;
              const float* ep = embed + (size_t)v * 32;
              float dot = 0.f, sz = 0.f;
#pragma unroll 1
              for (int i = 0; i < 32; ++i) {
                float zc = zp[i];
                dot = fmaf(zc, ep[i], dot);
                sz  = fmaf(zc, zc, sz);
              }
              float d = fmaf(-2.0f, dot, sz) + se[v];
              unsigned long long key =
                  ((unsigned long long)encf(d) << 32) | (unsigned)v;
              atomicMin(&keys[n], key);
            }
          }
        }
      }
    }
  }

  // batch exact-fp32 rescue (dot and sz both accumulate ascending c --
  // identical fp order to the passing formula)
  __syncthreads();
  int tot = min(ccnt, CAP);
  for (int j = tid; j < tot; j += 256) {
    unsigned long long cv = clist[j];
    int n = min((int)(cv >> 32), nmax - 1);
    int v = min((int)(cv & 0xffffffffull), V_ - 1);
    const float* zp = zrow + (size_t)n * 32;
    const float* ep = embed + (size_t)v * 32;
    float dot = 0.f, sz = 0.f;
#pragma unroll
    for (int i = 0; i < 32; ++i) {
      float zc = zp[i];
      dot = fmaf(zc, ep[i], dot);
      sz  = fmaf(zc, zc, sz);
    }
    float d = fmaf(-2.0f, dot, sz) + se[v];
    unsigned long long key =
        ((unsigned long long)encf(d) << 32) | (unsigned)v;
    atomicMin(&keys[n], key);
  }
}

// ---- upsample + f_rest update + loss + idx out + next-scale prep ----
// block = one (b,c) plane; blockIdx.x = b*32+c; tid = o*16+p
__global__ __launch_bounds__(256) void up_update_kernel(
    const float* __restrict__ embed, const unsigned long long* __restrict__ keys,
    const float* __restrict__ tbl, float* __restrict__ f_rest, int pn,
    float* __restrict__ zrow, short* __restrict__ zrowb,
    unsigned long long* __restrict__ keys_nb, unsigned int* __restrict__ smin_nb,
    int pn_next, int n_next,
    float* __restrict__ idx_out, float* __restrict__ loss_slot)
{
  __shared__ float sm[256];
  __shared__ float sm_e[64];
  const int tid = threadIdx.x;
  const int t = blockIdx.x * 256 + tid;
  const int p = tid & 15, o = tid >> 4;
  const int c = blockIdx.x & 31, b = blockIdx.x >> 5;
  const int pn2 = pn * pn;

  float pre = f_rest[t];
  sm[tid] = pre;
  if (tid < pn2) {
    int idx = keyidx(keys[b * pn2 + tid]);
    if (c == 0) idx_out[b * pn2 + tid] = (float)idx;
    sm_e[tid] = embed[(size_t)idx * 32 + c];
  }
  __syncthreads();

  // loss partial: recompute zavg from pre-update plane (== zrow exactly)
  float lsum = 0.f;
  if (tid < pn2) {
    int k = 16 / pn;
    int ph = tid / pn, pw = tid - ph * pn;
    float s = 0.f;
    for (int i = 0; i < k; ++i)
      for (int j = 0; j < k; ++j)
        s += sm[(ph * k + i) * 16 + (pw * k + j)];
    float zavg = s * (1.0f / (k * k));
    float d = sm_e[tid] - zavg;
    lsum = d * d;
  }
#pragma unroll
  for (int off = 32; off > 0; off >>= 1) lsum += __shfl_down(lsum, off, 64);
  if ((tid & 63) == 0)
    atomicAdd(loss_slot + ((blockIdx.x & 127) << 4), lsum);

  // bicubic upsample (ref: h-einsum first, then w)
  const float* Wo = tbl + o * 8;
  const float* Wp = tbl + p * 8;
  float acc = 0.f;
  for (int w = 0; w < pn; ++w) {
    float inner = 0.f;
    for (int h = 0; h < pn; ++h)
      inner = fmaf(Wo[h], sm_e[h * pn + w], inner);
    acc = fmaf(Wp[w], inner, acc);
  }
  float nr = pre - acc;
  f_rest[t] = nr;

  __syncthreads();
  sm[tid] = nr;
  __syncthreads();
  const int pnn2 = pn_next * pn_next;
  if (tid < pnn2) {
    int ph = tid / pn_next, pw = tid - ph * pn_next;
    int k = 16 / pn_next;
    float s = 0.f;
    for (int i = 0; i < k; ++i)
      for (int j = 0; j < k; ++j)
        s += sm[(ph * k + i) * 16 + (pw * k + j)];
    float zavg = s * (1.0f / (k * k));
    size_t nn = (size_t)(b * pnn2 + tid);
    zrow[nn * 32 + c]  = zavg;          // exact f32 for rescue/loss
    zrowb[nn * 32 + c] = f2bf(-zavg);   // negated bf16, 2nd-operand source
  }
  if (t < n_next) {                // reset ping-pong buffers for next scale
    keys_nb[t] = ~0ull;
    smin_nb[t] = 0xFFFFFFFFu;
  }
}

// -- final scale (pn=16): out = (z - f_rest) + embed[idx], idx out, loss --
__global__ __launch_bounds__(256) void final_add_kernel(
    const float* __restrict__ z, const float* __restrict__ f_rest,
    const float* __restrict__ embed, const unsigned long long* __restrict__ keys,
    float* __restrict__ f_hat, float* __restrict__ idx_out,
    float* __restrict__ loss_slot)
{
  const int tid = threadIdx.x;
  const int t = blockIdx.x * 256 + tid;
  const int c = blockIdx.x & 31, b = blockIdx.x >> 5;
  const int n = b * 256 + tid;
  int idx = keyidx(keys[n]);
  if (c == 0) idx_out[n] = (float)idx;
  float e = embed[(size_t)idx * 32 + c];
  float fr = f_rest[t];
  f_hat[t] = (z[t] - fr) + e;   // f_hat = sum of zq (err ~1e-6)
  float d = e - fr;             // fr == zavg at pn=16 bit-exactly
  float lsum = d * d;
#pragma unroll
  for (int off = 32; off > 0; off >>= 1) lsum += __shfl_down(lsum, off, 64);
  if ((tid & 63) == 0)
    atomicAdd(loss_slot + ((blockIdx.x & 127) << 4), lsum);
}

// ------------- final loss reduce: 5 scales x 128 padded slots -------------
__global__ __launch_bounds__(128) void loss_final_kernel(
    const float* __restrict__ loss_slots, float* __restrict__ out_loss)
{
  __shared__ float lred[2];
  const int tid = threadIdx.x;   // 128 threads = 2 waves
  const float numel[5] = {8192.f, 32768.f, 131072.f, 524288.f, 2097152.f};
  float tot = 0.f;
  for (int s = 0; s < 5; ++s) {
    float x = loss_slots[s * 2048 + tid * 16];
#pragma unroll
    for (int off = 32; off > 0; off >>= 1) x += __shfl_down(x, off, 64);
    if ((tid & 63) == 0) lred[tid >> 6] = x;
    __syncthreads();
    if (tid == 0) {
      float m = (lred[0] + lred[1]) / numel[s];
      tot += 0.25f * m + m;        // beta*mean + mean
    }
    __syncthreads();
  }
  if (tid == 0) out_loss[0] = tot / 5.f;
}

// =========================== host launcher ===========================
extern "C" void kernel_launch(void* const* d_in, const int* in_sizes, int n_in,
                              void* d_out, int out_size, void* d_ws, size_t ws_size,
                              hipStream_t stream)
{
  const float* z     = (const float*)d_in[0];
  const float* embed = (const float*)d_in[1];
  float* out = (float*)d_out;
  float* ws  = (float*)d_ws;

  // ws layout (float slots), total 5573120 floats ~= 21.3 MiB
  float* f_rest  = ws;                                   // 2097152
  float* zrow    = ws + 2097152;                         // [65536][32] f32
  short* zrowb   = (short*)(ws + 4194304);               // [65536][32] bf16(-z)
  short* ebf     = (short*)(ws + 5242880);               // 131072 shorts
  float* se      = ws + 5308416;                         // 4096
  float* sehalf  = ws + 5312512;                         // 4096
  unsigned int* smin0 = (unsigned int*)(ws + 5316608);   // 65536 u32
  unsigned int* smin1 = (unsigned int*)(ws + 5382144);   // 16384 u32
  unsigned long long* keys0 = (unsigned long long*)(ws + 5398528); // 65536 u64
  unsigned long long* keys1 = (unsigned long long*)(ws + 5529600); // 16384 u64
  float* loss_slots = ws + 5562368;                      // 5*128*16 = 10240
  float* tables     = ws + 5572608;                      // 512

  unsigned long long* keysb[2] = {keys0, keys1};
  unsigned int*       sminb[2] = {smin0, smin1};

  setup_kernel<<<NTOT / 256, 256, 0, stream>>>(z, embed, f_rest, zrow, zrowb,
                                               ebf, se, sehalf, tables,
                                               loss_slots, keys0, smin0);

  const int PN[5]  = {1, 2, 4, 8, 16};
  // giter: 16-point groups streamed per wave (points/block = 16*giter)
  const int GIT[5] = {1, 2, 4, 8, 8};
  int idx_off = NTOT;
  for (int i = 0; i < 5; ++i) {
    int pn = PN[i];
    int N  = B_ * pn * pn;
    int giter = GIT[i];
    unsigned long long* kb = keysb[i & 1];
    unsigned int*       sb = sminb[i & 1];
    dim3 g(N / (16 * giter), V_ / 512);       // 4 waves x 128 codes = 512/blk
    vq_phaseA_kernel<<<g, 256, 0, stream>>>(zrowb, ebf, sehalf, sb, giter);
    vq_phaseB_kernel<<<g, 256, 0, stream>>>(zrowb, ebf, sehalf, sb, zrow,
                                            embed, se, kb, giter, N);
    if (i < 4) {
      int pnn = PN[i + 1];
      up_update_kernel<<<NTOT / 256, 256, 0, stream>>>(
          embed, kb, tables + i * 128, f_rest, pn,
          zrow, zrowb, keysb[(i + 1) & 1], sminb[(i + 1) & 1],
          pnn, B_ * pnn * pnn, out + idx_off, loss_slots + i * 2048);
    } else {
      final_add_kernel<<<NTOT / 256, 256, 0, stream>>>(
          z, f_rest, embed, kb, out, out + idx_off, loss_slots + 4 * 2048);
    }
    idx_off += N;
  }
  loss_final_kernel<<<1, 128, 0, stream>>>(loss_slots, out + 2184448);
}

// Round 8
// 396.468 us; speedup vs baseline: 1.1077x; 1.1077x over previous
//
#include <hip/hip_runtime.h>
#include <hip/hip_bf16.h>
#include <cstdint>
#include <cstddef>

// MultiScaleQuantizer: z (256,32,16,16) fp32, embed (4096,32) fp32.
// Outputs concat (fp32): f_hat (2097152), idx@pn=1..16 (87296), loss (1).
//
// r24 = r16's proven structure (380us; every structural rewrite r17-r23
// lost to the occupancy/latency trade: dur ~ 1/occupancy with constant
// product) + ONLY the operand-sourcing fixes verified correct in four
// passing rounds (r19-r23):
//  1) A-frags: one coalesced 16B load from pre-negated bf16 zrowb
//     (replaces 16 strided 256KB-apart f32 loads + 16 f2bf per frag).
//  2) Rescue/fallback: contiguous zrow rows (r16 read zp[i*65536]: 32
//     scattered lines per candidate; now 2).
//  3) final_add loss from f_rest (== zavg bit-exact at pn16); zpack
//     col-major buffer deleted.
// Schedule, tiling, thresholds, CAP, MARGIN, LDS layout: identical to r16.

#define B_   256
#define V_   4096
#define NTOT 2097152   // 256*32*16*16
#define WIN  128       // codebook window staged in LDS
#define CAP  512       // candidate list capacity per block
#define MARGIN_ 1.0f

using bf16x8 = __attribute__((ext_vector_type(8))) short;
using f32x4  = __attribute__((ext_vector_type(4))) float;

__device__ inline short f2bf(float f) {
  __hip_bfloat16 h = __float2bfloat16(f);
  return *reinterpret_cast<short*>(&h);
}
__device__ inline unsigned encf(float f) {        // monotone fp32 -> u32
  unsigned u = __float_as_uint(f);
  return (u & 0x80000000u) ? ~u : (u | 0x80000000u);
}
__device__ inline float decf(unsigned u) {
  unsigned b = (u & 0x80000000u) ? (u ^ 0x80000000u) : ~u;
  return __uint_as_float(b);
}
__device__ inline int keyidx(unsigned long long k) {  // decode + clamp (safety)
  int i = (int)(unsigned)(k & 0xffffffffull);
  return min(max(i, 0), V_ - 1);
}
__device__ inline float min3f(float a, float b, float c) {
  float d;
  asm("v_min3_f32 %0, %1, %2, %3" : "=v"(d) : "v"(a), "v"(b), "v"(c));
  return d;
}

// ---- setup: f_rest=z, zrow/zrowb@pn1, ebf, se, tables, inits ----
// block = one (b,c) plane; blockIdx.x = b*32+c
__global__ __launch_bounds__(256) void setup_kernel(
    const float* __restrict__ z, const float* __restrict__ embed,
    float* __restrict__ f_rest, float* __restrict__ zrow,
    short* __restrict__ zrowb, short* __restrict__ ebf,
    float* __restrict__ se, float* __restrict__ tables,
    float* __restrict__ loss_slots, unsigned long long* __restrict__ keys0,
    unsigned int* __restrict__ smin0)
{
  const int tid = threadIdx.x;
  const int t = blockIdx.x * 256 + tid;
  float v = z[t];
  f_rest[t] = v;

  __shared__ float sm[256];
  sm[tid] = v;
  __syncthreads();
  if (tid == 0) {
    float s = 0.f;
    for (int i = 0; i < 256; ++i) s += sm[i];   // ref's linear i,j order
    int c = blockIdx.x & 31, b = blockIdx.x >> 5;
    float val = s * (1.0f / 256.0f);
    zrow[(size_t)b * 32 + c] = val;             // row-major [n][32]
    zrowb[(size_t)b * 32 + c] = f2bf(-val);     // negated bf16 A-frag source
  }

  if (blockIdx.x < 16) {                        // se + ebf: 16*256 codes
    int code = blockIdx.x * 256 + tid;
    float s = 0.f;
#pragma unroll
    for (int c = 0; c < 32; ++c) {
      float e = embed[(size_t)code * 32 + c];
      ebf[(size_t)code * 32 + c] = f2bf(e);
      s += e * e;                                // sequential like ref
    }
    se[code] = s;
  } else if (blockIdx.x == 16) {
    if (tid < 64) {
      int pn_i = tid >> 4;          // 0..3 -> pn = 1,2,4,8
      int o    = tid & 15;
      int pn   = 1 << pn_i;
      double scale = (double)pn / 16.0;
      double x  = (o + 0.5) * scale - 0.5;
      double x0 = floor(x);
      double tf = x - x0;
      float row[8];
#pragma unroll
      for (int h = 0; h < 8; ++h) row[h] = 0.f;
      const double A = -0.75;
#pragma unroll
      for (int off = -1; off <= 2; ++off) {
        double s = fabs(tf - (double)off);
        double cub;
        if (s <= 1.0)      cub = ((A + 2.0) * s - (A + 3.0)) * s * s + 1.0;
        else if (s < 2.0)  cub = (((s - 5.0) * s + 8.0) * s - 4.0) * A;
        else               cub = 0.0;
        int idx = (int)x0 + off;
        idx = min(max(idx, 0), pn - 1);
        row[idx] = (float)((double)row[idx] + cub);  // numpy f32 += f64
      }
#pragma unroll
      for (int h = 0; h < 8; ++h) tables[pn_i * 128 + o * 8 + h] = row[h];
    }
  } else if (blockIdx.x == 17) {
    keys0[tid] = ~0ull;                          // pn=1: N=256
    smin0[tid] = 0xFFFFFFFFu;
  } else if (blockIdx.x >= 20 && blockIdx.x < 60) {
    loss_slots[(blockIdx.x - 20) * 256 + tid] = 0.f;   // 40*256 = 10240 zeros
  }
}

// ---------------- phase A: MFMA scan -> per-point min of s=se/2-dot ----------
// block 256 = 4 waves x 32 points (2 frags/wave); grid.x = N/128,
// grid.y = v-chunks
__global__ __launch_bounds__(256) void vq_phaseA_kernel(
    const short* __restrict__ zrowb, const short* __restrict__ ebf,
    const float* __restrict__ se, unsigned int* __restrict__ smin,
    int vchunk)
{
  __shared__ __align__(16) short elds[WIN * 40]; // padded stride 80B rows
  __shared__ float selds[WIN];

  const int tid = threadIdx.x;
  const int lane = tid & 63, wave = tid >> 6;
  const int col = lane & 15, quad = lane >> 4;
  const int nw = blockIdx.x * 128 + wave * 32;
  const int vbase = blockIdx.y * vchunk;

  // A-frags: one coalesced 16B load each from pre-negated bf16 z rows
  bf16x8 af[2];
#pragma unroll
  for (int f = 0; f < 2; ++f)
    af[f] = *(const bf16x8*)(zrowb + (size_t)(nw + f * 16 + col) * 32 + quad * 8);

  float mn[2][4];
#pragma unroll
  for (int f = 0; f < 2; ++f)
#pragma unroll
    for (int r = 0; r < 4; ++r) mn[f][r] = 3.4e38f;

  for (int w0 = 0; w0 < vchunk; w0 += WIN) {
    __syncthreads();
    {
      // 128 rows x 2 threads; each thread stores 2 bf16x8 = full 32-short row
      int row = tid >> 1, half = tid & 1;
      const bf16x8* src = (const bf16x8*)(ebf + (size_t)(vbase + w0 + row) * 32);
      bf16x8* dst = (bf16x8*)(elds + row * 40);
      dst[half * 2]     = src[half * 2];
      dst[half * 2 + 1] = src[half * 2 + 1];
      if (tid < WIN) selds[tid] = 0.5f * se[vbase + w0 + tid];  // *0.5 exact
    }
    __syncthreads();
    for (int vv = 0; vv < WIN; vv += 16) {
      bf16x8 bf = *(const bf16x8*)(elds + (vv + col) * 40 + quad * 8);
      float sevh = selds[vv + col];
      f32x4 cin = {sevh, sevh, sevh, sevh};       // D = se/2 + (-z)*e
#pragma unroll
      for (int f = 0; f < 2; ++f) {
        f32x4 d = __builtin_amdgcn_mfma_f32_16x16x32_bf16(af[f], bf, cin, 0, 0, 0);
#pragma unroll
        for (int r = 0; r < 4; ++r) mn[f][r] = fminf(mn[f][r], d[r]);
      }
    }
  }
  // cross-col min via shuffle butterfly
#pragma unroll
  for (int f = 0; f < 2; ++f)
#pragma unroll
    for (int r = 0; r < 4; ++r) {
      float m = mn[f][r];
      m = fminf(m, __shfl_xor(m, 1, 64));
      m = fminf(m, __shfl_xor(m, 2, 64));
      m = fminf(m, __shfl_xor(m, 4, 64));
      m = fminf(m, __shfl_xor(m, 8, 64));
      mn[f][r] = m;
    }
  if (col == 0) {
#pragma unroll
    for (int f = 0; f < 2; ++f)
#pragma unroll
      for (int r = 0; r < 4; ++r)
        atomicMin(&smin[nw + f * 16 + quad * 4 + r], encf(mn[f][r]));
  }
}

// -------- phase B: MFMA re-scan; candidates -> LDS list -> batch rescue -----
__global__ __launch_bounds__(256) void vq_phaseB_kernel(
    const short* __restrict__ zrowb, const short* __restrict__ ebf,
    const float* __restrict__ se, const unsigned int* __restrict__ smin,
    const float* __restrict__ zrow, const float* __restrict__ embed,
    unsigned long long* __restrict__ keys, int vchunk, int nmax)
{
  __shared__ __align__(16) short elds[WIN * 40];
  __shared__ float selds[WIN];
  __shared__ unsigned long long clist[CAP];
  __shared__ int ccnt;

  const int tid = threadIdx.x;
  const int lane = tid & 63, wave = tid >> 6;
  const int col = lane & 15, quad = lane >> 4;
  const int nw = blockIdx.x * 128 + wave * 32;
  const int vbase = blockIdx.y * vchunk;

  if (tid == 0) ccnt = 0;
  __syncthreads();

  bf16x8 af[2];
#pragma unroll
  for (int f = 0; f < 2; ++f)
    af[f] = *(const bf16x8*)(zrowb + (size_t)(nw + f * 16 + col) * 32 + quad * 8);

  float thr[2][4];
#pragma unroll
  for (int f = 0; f < 2; ++f)
#pragma unroll
    for (int r = 0; r < 4; ++r)
      thr[f][r] = decf(smin[nw + f * 16 + quad * 4 + r]) + MARGIN_;
  // per-lane coarse bound: max of this lane's 8 per-point thresholds
  float tmax = fmaxf(
      fmaxf(fmaxf(thr[0][0], thr[0][1]), fmaxf(thr[0][2], thr[0][3])),
      fmaxf(fmaxf(thr[1][0], thr[1][1]), fmaxf(thr[1][2], thr[1][3])));

  for (int w0 = 0; w0 < vchunk; w0 += WIN) {
    __syncthreads();
    {
      int row = tid >> 1, half = tid & 1;       // full-row staging (see A)
      const bf16x8* src = (const bf16x8*)(ebf + (size_t)(vbase + w0 + row) * 32);
      bf16x8* dst = (bf16x8*)(elds + row * 40);
      dst[half * 2]     = src[half * 2];
      dst[half * 2 + 1] = src[half * 2 + 1];
      if (tid < WIN) selds[tid] = 0.5f * se[vbase + w0 + tid];
    }
    __syncthreads();
    for (int vv = 0; vv < WIN; vv += 16) {
      bf16x8 bf = *(const bf16x8*)(elds + (vv + col) * 40 + quad * 8);
      float sevh = selds[vv + col];
      f32x4 cin = {sevh, sevh, sevh, sevh};
      f32x4 dd[2];
      dd[0] = __builtin_amdgcn_mfma_f32_16x16x32_bf16(af[0], bf, cin, 0, 0, 0);
      dd[1] = __builtin_amdgcn_mfma_f32_16x16x32_bf16(af[1], bf, cin, 0, 0, 0);
      // coarse gate: min of 8 vs max of 8 thrs (no false negatives)
      float a = min3f(dd[0][0], dd[0][1], dd[0][2]);
      float b = min3f(dd[0][3], dd[1][0], dd[1][1]);
      float c = min3f(dd[1][2], dd[1][3], a);
      if (fminf(b, c) <= tmax) {   // drill down per element (rare)
#pragma unroll
        for (int f = 0; f < 2; ++f) {
#pragma unroll
          for (int r = 0; r < 4; ++r) {
            if (dd[f][r] <= thr[f][r]) {
              int n = nw + f * 16 + quad * 4 + r;
              int v = vbase + w0 + vv + col;
              int slot = atomicAdd(&ccnt, 1);   // LDS atomic: fast
              if (slot < CAP) {
                clist[slot] =
                    ((unsigned long long)(unsigned)n << 32) | (unsigned)v;
              } else {
                // overflow fallback: exact inline (ascending-c fp order)
                const float* zp = zrow + (size_t)n * 32;
                const float* ep = embed + (size_t)v * 32;
                float dot = 0.f, sz = 0.f;
#pragma unroll 1
                for (int i = 0; i < 32; ++i) {
                  float zc = zp[i];
                  dot = fmaf(zc, ep[i], dot);
                  sz  = fmaf(zc, zc, sz);
                }
                float d = fmaf(-2.0f, dot, sz) + se[v];
                unsigned long long key =
                    ((unsigned long long)encf(d) << 32) | (unsigned)v;
                atomicMin(&keys[n], key);
              }
            }
          }
        }
      }
    }
  }

  // batch exact-fp32 rescue (dot and sz both accumulate ascending c --
  // identical fp order to the passing formula; zrow rows contiguous)
  __syncthreads();
  int tot = min(ccnt, CAP);
  for (int j = tid; j < tot; j += 256) {
    unsigned long long cv = clist[j];
    int n = min((int)(cv >> 32), nmax - 1);
    int v = min((int)(cv & 0xffffffffull), V_ - 1);
    const float* zp = zrow + (size_t)n * 32;
    const float* ep = embed + (size_t)v * 32;
    float dot = 0.f, sz = 0.f;
#pragma unroll
    for (int i = 0; i < 32; ++i) {
      float zc = zp[i];
      dot = fmaf(zc, ep[i], dot);
      sz  = fmaf(zc, zc, sz);
    }
    float d = fmaf(-2.0f, dot, sz) + se[v];
    unsigned long long key =
        ((unsigned long long)encf(d) << 32) | (unsigned)v;
    atomicMin(&keys[n], key);
  }
}

// ---- upsample + f_rest update + loss + idx out + next-scale prep ----
// block = one (b,c) plane; blockIdx.x = b*32+c; tid = o*16+p
__global__ __launch_bounds__(256) void up_update_kernel(
    const float* __restrict__ embed, const unsigned long long* __restrict__ keys,
    const float* __restrict__ tbl, float* __restrict__ f_rest, int pn,
    float* __restrict__ zrow, short* __restrict__ zrowb,
    unsigned long long* __restrict__ keys_nb, unsigned int* __restrict__ smin_nb,
    int pn_next, int n_next,
    float* __restrict__ idx_out, float* __restrict__ loss_slot)
{
  __shared__ float sm[256];
  __shared__ float sm_e[64];
  const int tid = threadIdx.x;
  const int t = blockIdx.x * 256 + tid;
  const int p = tid & 15, o = tid >> 4;
  const int c = blockIdx.x & 31, b = blockIdx.x >> 5;
  const int pn2 = pn * pn;

  float pre = f_rest[t];
  sm[tid] = pre;
  if (tid < pn2) {
    int idx = keyidx(keys[b * pn2 + tid]);
    if (c == 0) idx_out[b * pn2 + tid] = (float)idx;
    sm_e[tid] = embed[(size_t)idx * 32 + c];
  }
  __syncthreads();

  // loss partial: recompute zavg from pre-update plane (== zrow exactly)
  float lsum = 0.f;
  if (tid < pn2) {
    int k = 16 / pn;
    int ph = tid / pn, pw = tid - ph * pn;
    float s = 0.f;
    for (int i = 0; i < k; ++i)
      for (int j = 0; j < k; ++j)
        s += sm[(ph * k + i) * 16 + (pw * k + j)];
    float zavg = s * (1.0f / (k * k));
    float d = sm_e[tid] - zavg;
    lsum = d * d;
  }
#pragma unroll
  for (int off = 32; off > 0; off >>= 1) lsum += __shfl_down(lsum, off, 64);
  if ((tid & 63) == 0)
    atomicAdd(loss_slot + ((blockIdx.x & 127) << 4), lsum);

  // bicubic upsample (ref: h-einsum first, then w)
  const float* Wo = tbl + o * 8;
  const float* Wp = tbl + p * 8;
  float acc = 0.f;
  for (int w = 0; w < pn; ++w) {
    float inner = 0.f;
    for (int h = 0; h < pn; ++h)
      inner = fmaf(Wo[h], sm_e[h * pn + w], inner);
    acc = fmaf(Wp[w], inner, acc);
  }
  float nr = pre - acc;
  f_rest[t] = nr;

  __syncthreads();
  sm[tid] = nr;
  __syncthreads();
  const int pnn2 = pn_next * pn_next;
  if (tid < pnn2) {
    int ph = tid / pn_next, pw = tid - ph * pn_next;
    int k = 16 / pn_next;
    float s = 0.f;
    for (int i = 0; i < k; ++i)
      for (int j = 0; j < k; ++j)
        s += sm[(ph * k + i) * 16 + (pw * k + j)];
    float zavg = s * (1.0f / (k * k));
    size_t nn = (size_t)(b * pnn2 + tid);
    zrow[nn * 32 + c]  = zavg;          // exact f32 for rescue/loss
    zrowb[nn * 32 + c] = f2bf(-zavg);   // negated bf16 A-frag source
  }
  if (t < n_next) {                // reset ping-pong buffers for next scale
    keys_nb[t] = ~0ull;
    smin_nb[t] = 0xFFFFFFFFu;
  }
}

// -- final scale (pn=16): out = (z - f_rest) + embed[idx], idx out, loss --
__global__ __launch_bounds__(256) void final_add_kernel(
    const float* __restrict__ z, const float* __restrict__ f_rest,
    const float* __restrict__ embed, const unsigned long long* __restrict__ keys,
    float* __restrict__ f_hat, float* __restrict__ idx_out,
    float* __restrict__ loss_slot)
{
  const int tid = threadIdx.x;
  const int t = blockIdx.x * 256 + tid;
  const int c = blockIdx.x & 31, b = blockIdx.x >> 5;
  const int n = b * 256 + tid;
  int idx = keyidx(keys[n]);
  if (c == 0) idx_out[n] = (float)idx;
  float e = embed[(size_t)idx * 32 + c];
  float fr = f_rest[t];
  f_hat[t] = (z[t] - fr) + e;   // f_hat = sum of zq (err ~1e-6)
  float d = e - fr;             // fr == zavg at pn=16 bit-exactly
  float lsum = d * d;
#pragma unroll
  for (int off = 32; off > 0; off >>= 1) lsum += __shfl_down(lsum, off, 64);
  if ((tid & 63) == 0)
    atomicAdd(loss_slot + ((blockIdx.x & 127) << 4), lsum);
}

// ------------- final loss reduce: 5 scales x 128 padded slots -------------
__global__ __launch_bounds__(128) void loss_final_kernel(
    const float* __restrict__ loss_slots, float* __restrict__ out_loss)
{
  __shared__ float lred[2];
  const int tid = threadIdx.x;   // 128 threads = 2 waves
  const float numel[5] = {8192.f, 32768.f, 131072.f, 524288.f, 2097152.f};
  float tot = 0.f;
  for (int s = 0; s < 5; ++s) {
    float x = loss_slots[s * 2048 + tid * 16];
#pragma unroll
    for (int off = 32; off > 0; off >>= 1) x += __shfl_down(x, off, 64);
    if ((tid & 63) == 0) lred[tid >> 6] = x;
    __syncthreads();
    if (tid == 0) {
      float m = (lred[0] + lred[1]) / numel[s];
      tot += 0.25f * m + m;        // beta*mean + mean
    }
    __syncthreads();
  }
  if (tid == 0) out_loss[0] = tot / 5.f;
}

// =========================== host launcher ===========================
extern "C" void kernel_launch(void* const* d_in, const int* in_sizes, int n_in,
                              void* d_out, int out_size, void* d_ws, size_t ws_size,
                              hipStream_t stream)
{
  const float* z     = (const float*)d_in[0];
  const float* embed = (const float*)d_in[1];
  float* out = (float*)d_out;
  float* ws  = (float*)d_ws;

  // ws layout (float slots), total 5569024 floats ~= 21.2 MiB
  float* f_rest  = ws;                                   // 2097152
  float* zrow    = ws + 2097152;                         // [65536][32] f32
  short* zrowb   = (short*)(ws + 4194304);               // [65536][32] bf16(-z)
  short* ebf     = (short*)(ws + 5242880);               // 131072 shorts
  float* se      = ws + 5308416;                         // 4096
  unsigned int* smin0 = (unsigned int*)(ws + 5312512);   // 65536 u32
  unsigned int* smin1 = (unsigned int*)(ws + 5378048);   // 16384 u32
  unsigned long long* keys0 = (unsigned long long*)(ws + 5394432); // 65536 u64
  unsigned long long* keys1 = (unsigned long long*)(ws + 5525504); // 16384 u64
  float* loss_slots = ws + 5558272;                      // 5*128*16 = 10240
  float* tables     = ws + 5568512;                      // 512

  unsigned long long* keysb[2] = {keys0, keys1};
  unsigned int*       sminb[2] = {smin0, smin1};

  setup_kernel<<<NTOT / 256, 256, 0, stream>>>(z, embed, f_rest, zrow, zrowb,
                                               ebf, se, tables, loss_slots,
                                               keys0, smin0);

  const int PN[5]  = {1, 2, 4, 8, 16};
  const int NVC[5] = {32, 32, 32, 16, 16};  // v-chunks; vchunk multiple of WIN
  int idx_off = NTOT;
  for (int i = 0; i < 5; ++i) {
    int pn = PN[i];
    int N  = B_ * pn * pn;
    int vchunk = V_ / NVC[i];
    unsigned long long* kb = keysb[i & 1];
    unsigned int*       sb = sminb[i & 1];
    dim3 g(N / 128, NVC[i]);                  // 2-frag waves: 128 points/block
    vq_phaseA_kernel<<<g, 256, 0, stream>>>(zrowb, ebf, se, sb, vchunk);
    vq_phaseB_kernel<<<g, 256, 0, stream>>>(zrowb, ebf, se, sb, zrow, embed,
                                            kb, vchunk, N);
    if (i < 4) {
      int pnn = PN[i + 1];
      up_update_kernel<<<NTOT / 256, 256, 0, stream>>>(
          embed, kb, tables + i * 128, f_rest, pn,
          zrow, zrowb, keysb[(i + 1) & 1], sminb[(i + 1) & 1],
          pnn, B_ * pnn * pnn, out + idx_off, loss_slots + i * 2048);
    } else {
      final_add_kernel<<<NTOT / 256, 256, 0, stream>>>(
          z, f_rest, embed, kb, out, out + idx_off, loss_slots + 4 * 2048);
    }
    idx_off += N;
  }
  loss_final_kernel<<<1, 128, 0, stream>>>(loss_slots, out + 2184448);
}

// Round 9
// 385.863 us; speedup vs baseline: 1.1381x; 1.0275x over previous
//
#include <hip/hip_runtime.h>
#include <hip/hip_bf16.h>
#include <cstdint>
#include <cstddef>

// MultiScaleQuantizer: z (256,32,16,16) fp32, embed (4096,32) fp32.
// Outputs concat (fp32): f_hat (2097152), idx@pn=1..16 (87296), loss (1).
//
// r25 = r24 (scan operand fixes verified; phaseB left top-5) + the write-
// amplification fix for up_update, which r24's rocprof exposed as the new
// top dispatch (75us, WRITE_SIZE=108MB vs ~12MB useful): per-(b,c) blocks
// writing row-major zrow[n*32+c] are 2M isolated 4B/2B stores -> ~10x
// sector amplification. Fix: producer writes COL-major zcol[c*65536+n]
// (coalesced across tid, as r16's zpack did), and a small LDS-tile
// transpose kernel emits the row-major zrow (f32) + zrowb (bf16(-v)) the
// scan wants. Values are bit-exact pass-throughs. zcol reuses the f_hat
// region of d_out as scratch (final_add overwrites it last) -> no ws growth.

#define B_   256
#define V_   4096
#define NTOT 2097152   // 256*32*16*16
#define WIN  128       // codebook window staged in LDS
#define CAP  512       // candidate list capacity per block
#define MARGIN_ 1.0f

using bf16x8 = __attribute__((ext_vector_type(8))) short;
using f32x4  = __attribute__((ext_vector_type(4))) float;

__device__ inline short f2bf(float f) {
  __hip_bfloat16 h = __float2bfloat16(f);
  return *reinterpret_cast<short*>(&h);
}
__device__ inline unsigned encf(float f) {        // monotone fp32 -> u32
  unsigned u = __float_as_uint(f);
  return (u & 0x80000000u) ? ~u : (u | 0x80000000u);
}
__device__ inline float decf(unsigned u) {
  unsigned b = (u & 0x80000000u) ? (u ^ 0x80000000u) : ~u;
  return __uint_as_float(b);
}
__device__ inline int keyidx(unsigned long long k) {  // decode + clamp (safety)
  int i = (int)(unsigned)(k & 0xffffffffull);
  return min(max(i, 0), V_ - 1);
}
__device__ inline float min3f(float a, float b, float c) {
  float d;
  asm("v_min3_f32 %0, %1, %2, %3" : "=v"(d) : "v"(a), "v"(b), "v"(c));
  return d;
}

// ---- setup: f_rest=z, zrow/zrowb@pn1, ebf, se, tables, inits ----
// block = one (b,c) plane; blockIdx.x = b*32+c
__global__ __launch_bounds__(256) void setup_kernel(
    const float* __restrict__ z, const float* __restrict__ embed,
    float* __restrict__ f_rest, float* __restrict__ zrow,
    short* __restrict__ zrowb, short* __restrict__ ebf,
    float* __restrict__ se, float* __restrict__ tables,
    float* __restrict__ loss_slots, unsigned long long* __restrict__ keys0,
    unsigned int* __restrict__ smin0)
{
  const int tid = threadIdx.x;
  const int t = blockIdx.x * 256 + tid;
  float v = z[t];
  f_rest[t] = v;

  __shared__ float sm[256];
  sm[tid] = v;
  __syncthreads();
  if (tid == 0) {
    float s = 0.f;
    for (int i = 0; i < 256; ++i) s += sm[i];   // ref's linear i,j order
    int c = blockIdx.x & 31, b = blockIdx.x >> 5;
    float val = s * (1.0f / 256.0f);
    zrow[(size_t)b * 32 + c] = val;             // row-major [n][32] (tiny @pn1)
    zrowb[(size_t)b * 32 + c] = f2bf(-val);     // negated bf16 A-frag source
  }

  if (blockIdx.x < 16) {                        // se + ebf: 16*256 codes
    int code = blockIdx.x * 256 + tid;
    float s = 0.f;
#pragma unroll
    for (int c = 0; c < 32; ++c) {
      float e = embed[(size_t)code * 32 + c];
      ebf[(size_t)code * 32 + c] = f2bf(e);
      s += e * e;                                // sequential like ref
    }
    se[code] = s;
  } else if (blockIdx.x == 16) {
    if (tid < 64) {
      int pn_i = tid >> 4;          // 0..3 -> pn = 1,2,4,8
      int o    = tid & 15;
      int pn   = 1 << pn_i;
      double scale = (double)pn / 16.0;
      double x  = (o + 0.5) * scale - 0.5;
      double x0 = floor(x);
      double tf = x - x0;
      float row[8];
#pragma unroll
      for (int h = 0; h < 8; ++h) row[h] = 0.f;
      const double A = -0.75;
#pragma unroll
      for (int off = -1; off <= 2; ++off) {
        double s = fabs(tf - (double)off);
        double cub;
        if (s <= 1.0)      cub = ((A + 2.0) * s - (A + 3.0)) * s * s + 1.0;
        else if (s < 2.0)  cub = (((s - 5.0) * s + 8.0) * s - 4.0) * A;
        else               cub = 0.0;
        int idx = (int)x0 + off;
        idx = min(max(idx, 0), pn - 1);
        row[idx] = (float)((double)row[idx] + cub);  // numpy f32 += f64
      }
#pragma unroll
      for (int h = 0; h < 8; ++h) tables[pn_i * 128 + o * 8 + h] = row[h];
    }
  } else if (blockIdx.x == 17) {
    keys0[tid] = ~0ull;                          // pn=1: N=256
    smin0[tid] = 0xFFFFFFFFu;
  } else if (blockIdx.x >= 20 && blockIdx.x < 60) {
    loss_slots[(blockIdx.x - 20) * 256 + tid] = 0.f;   // 40*256 = 10240 zeros
  }
}

// ---------------- phase A: MFMA scan -> per-point min of s=se/2-dot ----------
// block 256 = 4 waves x 32 points (2 frags/wave); grid.x = N/128,
// grid.y = v-chunks
__global__ __launch_bounds__(256) void vq_phaseA_kernel(
    const short* __restrict__ zrowb, const short* __restrict__ ebf,
    const float* __restrict__ se, unsigned int* __restrict__ smin,
    int vchunk)
{
  __shared__ __align__(16) short elds[WIN * 40]; // padded stride 80B rows
  __shared__ float selds[WIN];

  const int tid = threadIdx.x;
  const int lane = tid & 63, wave = tid >> 6;
  const int col = lane & 15, quad = lane >> 4;
  const int nw = blockIdx.x * 128 + wave * 32;
  const int vbase = blockIdx.y * vchunk;

  // A-frags: one coalesced 16B load each from pre-negated bf16 z rows
  bf16x8 af[2];
#pragma unroll
  for (int f = 0; f < 2; ++f)
    af[f] = *(const bf16x8*)(zrowb + (size_t)(nw + f * 16 + col) * 32 + quad * 8);

  float mn[2][4];
#pragma unroll
  for (int f = 0; f < 2; ++f)
#pragma unroll
    for (int r = 0; r < 4; ++r) mn[f][r] = 3.4e38f;

  for (int w0 = 0; w0 < vchunk; w0 += WIN) {
    __syncthreads();
    {
      // 128 rows x 2 threads; each thread stores 2 bf16x8 = full 32-short row
      int row = tid >> 1, half = tid & 1;
      const bf16x8* src = (const bf16x8*)(ebf + (size_t)(vbase + w0 + row) * 32);
      bf16x8* dst = (bf16x8*)(elds + row * 40);
      dst[half * 2]     = src[half * 2];
      dst[half * 2 + 1] = src[half * 2 + 1];
      if (tid < WIN) selds[tid] = 0.5f * se[vbase + w0 + tid];  // *0.5 exact
    }
    __syncthreads();
    for (int vv = 0; vv < WIN; vv += 16) {
      bf16x8 bf = *(const bf16x8*)(elds + (vv + col) * 40 + quad * 8);
      float sevh = selds[vv + col];
      f32x4 cin = {sevh, sevh, sevh, sevh};       // D = se/2 + (-z)*e
#pragma unroll
      for (int f = 0; f < 2; ++f) {
        f32x4 d = __builtin_amdgcn_mfma_f32_16x16x32_bf16(af[f], bf, cin, 0, 0, 0);
#pragma unroll
        for (int r = 0; r < 4; ++r) mn[f][r] = fminf(mn[f][r], d[r]);
      }
    }
  }
  // cross-col min via shuffle butterfly
#pragma unroll
  for (int f = 0; f < 2; ++f)
#pragma unroll
    for (int r = 0; r < 4; ++r) {
      float m = mn[f][r];
      m = fminf(m, __shfl_xor(m, 1, 64));
      m = fminf(m, __shfl_xor(m, 2, 64));
      m = fminf(m, __shfl_xor(m, 4, 64));
      m = fminf(m, __shfl_xor(m, 8, 64));
      mn[f][r] = m;
    }
  if (col == 0) {
#pragma unroll
    for (int f = 0; f < 2; ++f)
#pragma unroll
      for (int r = 0; r < 4; ++r)
        atomicMin(&smin[nw + f * 16 + quad * 4 + r], encf(mn[f][r]));
  }
}

// -------- phase B: MFMA re-scan; candidates -> LDS list -> batch rescue -----
__global__ __launch_bounds__(256) void vq_phaseB_kernel(
    const short* __restrict__ zrowb, const short* __restrict__ ebf,
    const float* __restrict__ se, const unsigned int* __restrict__ smin,
    const float* __restrict__ zrow, const float* __restrict__ embed,
    unsigned long long* __restrict__ keys, int vchunk, int nmax)
{
  __shared__ __align__(16) short elds[WIN * 40];
  __shared__ float selds[WIN];
  __shared__ unsigned long long clist[CAP];
  __shared__ int ccnt;

  const int tid = threadIdx.x;
  const int lane = tid & 63, wave = tid >> 6;
  const int col = lane & 15, quad = lane >> 4;
  const int nw = blockIdx.x * 128 + wave * 32;
  const int vbase = blockIdx.y * vchunk;

  if (tid == 0) ccnt = 0;
  __syncthreads();

  bf16x8 af[2];
#pragma unroll
  for (int f = 0; f < 2; ++f)
    af[f] = *(const bf16x8*)(zrowb + (size_t)(nw + f * 16 + col) * 32 + quad * 8);

  float thr[2][4];
#pragma unroll
  for (int f = 0; f < 2; ++f)
#pragma unroll
    for (int r = 0; r < 4; ++r)
      thr[f][r] = decf(smin[nw + f * 16 + quad * 4 + r]) + MARGIN_;
  // per-lane coarse bound: max of this lane's 8 per-point thresholds
  float tmax = fmaxf(
      fmaxf(fmaxf(thr[0][0], thr[0][1]), fmaxf(thr[0][2], thr[0][3])),
      fmaxf(fmaxf(thr[1][0], thr[1][1]), fmaxf(thr[1][2], thr[1][3])));

  for (int w0 = 0; w0 < vchunk; w0 += WIN) {
    __syncthreads();
    {
      int row = tid >> 1, half = tid & 1;       // full-row staging (see A)
      const bf16x8* src = (const bf16x8*)(ebf + (size_t)(vbase + w0 + row) * 32);
      bf16x8* dst = (bf16x8*)(elds + row * 40);
      dst[half * 2]     = src[half * 2];
      dst[half * 2 + 1] = src[half * 2 + 1];
      if (tid < WIN) selds[tid] = 0.5f * se[vbase + w0 + tid];
    }
    __syncthreads();
    for (int vv = 0; vv < WIN; vv += 16) {
      bf16x8 bf = *(const bf16x8*)(elds + (vv + col) * 40 + quad * 8);
      float sevh = selds[vv + col];
      f32x4 cin = {sevh, sevh, sevh, sevh};
      f32x4 dd[2];
      dd[0] = __builtin_amdgcn_mfma_f32_16x16x32_bf16(af[0], bf, cin, 0, 0, 0);
      dd[1] = __builtin_amdgcn_mfma_f32_16x16x32_bf16(af[1], bf, cin, 0, 0, 0);
      // coarse gate: min of 8 vs max of 8 thrs (no false negatives)
      float a = min3f(dd[0][0], dd[0][1], dd[0][2]);
      float b = min3f(dd[0][3], dd[1][0], dd[1][1]);
      float c = min3f(dd[1][2], dd[1][3], a);
      if (fminf(b, c) <= tmax) {   // drill down per element (rare)
#pragma unroll
        for (int f = 0; f < 2; ++f) {
#pragma unroll
          for (int r = 0; r < 4; ++r) {
            if (dd[f][r] <= thr[f][r]) {
              int n = nw + f * 16 + quad * 4 + r;
              int v = vbase + w0 + vv + col;
              int slot = atomicAdd(&ccnt, 1);   // LDS atomic: fast
              if (slot < CAP) {
                clist[slot] =
                    ((unsigned long long)(unsigned)n << 32) | (unsigned)v;
              } else {
                // overflow fallback: exact inline (ascending-c fp order)
                const float* zp = zrow + (size_t)n * 32;
                const float* ep = embed + (size_t)v * 32;
                float dot = 0.f, sz = 0.f;
#pragma unroll 1
                for (int i = 0; i < 32; ++i) {
                  float zc = zp[i];
                  dot = fmaf(zc, ep[i], dot);
                  sz  = fmaf(zc, zc, sz);
                }
                float d = fmaf(-2.0f, dot, sz) + se[v];
                unsigned long long key =
                    ((unsigned long long)encf(d) << 32) | (unsigned)v;
                atomicMin(&keys[n], key);
              }
            }
          }
        }
      }
    }
  }

  // batch exact-fp32 rescue (dot and sz both accumulate ascending c --
  // identical fp order to the passing formula; zrow rows contiguous)
  __syncthreads();
  int tot = min(ccnt, CAP);
  for (int j = tid; j < tot; j += 256) {
    unsigned long long cv = clist[j];
    int n = min((int)(cv >> 32), nmax - 1);
    int v = min((int)(cv & 0xffffffffull), V_ - 1);
    const float* zp = zrow + (size_t)n * 32;
    const float* ep = embed + (size_t)v * 32;
    float dot = 0.f, sz = 0.f;
#pragma unroll
    for (int i = 0; i < 32; ++i) {
      float zc = zp[i];
      dot = fmaf(zc, ep[i], dot);
      sz  = fmaf(zc, zc, sz);
    }
    float d = fmaf(-2.0f, dot, sz) + se[v];
    unsigned long long key =
        ((unsigned long long)encf(d) << 32) | (unsigned)v;
    atomicMin(&keys[n], key);
  }
}

// ---- upsample + f_rest update + loss + idx out + next-scale prep ----
// block = one (b,c) plane; blockIdx.x = b*32+c; tid = o*16+p
// zavg written COL-major (coalesced); transpose kernel makes row-major.
__global__ __launch_bounds__(256) void up_update_kernel(
    const float* __restrict__ embed, const unsigned long long* __restrict__ keys,
    const float* __restrict__ tbl, float* __restrict__ f_rest, int pn,
    float* __restrict__ zcol,
    unsigned long long* __restrict__ keys_nb, unsigned int* __restrict__ smin_nb,
    int pn_next, int n_next,
    float* __restrict__ idx_out, float* __restrict__ loss_slot)
{
  __shared__ float sm[256];
  __shared__ float sm_e[64];
  const int tid = threadIdx.x;
  const int t = blockIdx.x * 256 + tid;
  const int p = tid & 15, o = tid >> 4;
  const int c = blockIdx.x & 31, b = blockIdx.x >> 5;
  const int pn2 = pn * pn;

  float pre = f_rest[t];
  sm[tid] = pre;
  if (tid < pn2) {
    int idx = keyidx(keys[b * pn2 + tid]);
    if (c == 0) idx_out[b * pn2 + tid] = (float)idx;
    sm_e[tid] = embed[(size_t)idx * 32 + c];
  }
  __syncthreads();

  // loss partial: recompute zavg from pre-update plane
  float lsum = 0.f;
  if (tid < pn2) {
    int k = 16 / pn;
    int ph = tid / pn, pw = tid - ph * pn;
    float s = 0.f;
    for (int i = 0; i < k; ++i)
      for (int j = 0; j < k; ++j)
        s += sm[(ph * k + i) * 16 + (pw * k + j)];
    float zavg = s * (1.0f / (k * k));
    float d = sm_e[tid] - zavg;
    lsum = d * d;
  }
#pragma unroll
  for (int off = 32; off > 0; off >>= 1) lsum += __shfl_down(lsum, off, 64);
  if ((tid & 63) == 0)
    atomicAdd(loss_slot + ((blockIdx.x & 127) << 4), lsum);

  // bicubic upsample (ref: h-einsum first, then w)
  const float* Wo = tbl + o * 8;
  const float* Wp = tbl + p * 8;
  float acc = 0.f;
  for (int w = 0; w < pn; ++w) {
    float inner = 0.f;
    for (int h = 0; h < pn; ++h)
      inner = fmaf(Wo[h], sm_e[h * pn + w], inner);
    acc = fmaf(Wp[w], inner, acc);
  }
  float nr = pre - acc;
  f_rest[t] = nr;

  __syncthreads();
  sm[tid] = nr;
  __syncthreads();
  const int pnn2 = pn_next * pn_next;
  if (tid < pnn2) {
    int ph = tid / pn_next, pw = tid - ph * pn_next;
    int k = 16 / pn_next;
    float s = 0.f;
    for (int i = 0; i < k; ++i)
      for (int j = 0; j < k; ++j)
        s += sm[(ph * k + i) * 16 + (pw * k + j)];
    float zavg = s * (1.0f / (k * k));
    // col-major: consecutive tid -> consecutive addresses (coalesced)
    zcol[(size_t)c * 65536 + b * pnn2 + tid] = zavg;
  }
  if (t < n_next) {                // reset ping-pong buffers for next scale
    keys_nb[t] = ~0ull;
    smin_nb[t] = 0xFFFFFFFFu;
  }
}

// ---- transpose zcol [32][65536-stride] -> zrow [n][32] + zrowb bf16(-v) ----
// grid = n_next/64 blocks x 256 threads; fully coalesced in and out,
// LDS tile padded to 33 floats/row (conflict-free both phases).
__global__ __launch_bounds__(256) void zpack_transpose_kernel(
    const float* __restrict__ zcol, float* __restrict__ zrow,
    short* __restrict__ zrowb)
{
  __shared__ float tile[64][33];
  const int tid = threadIdx.x;
  const int nb = blockIdx.x * 64;
  const int pt = tid & 63, cg = tid >> 6;    // point, channel-group (0..3)
#pragma unroll
  for (int it = 0; it < 8; ++it) {
    int c = it * 4 + cg;
    tile[pt][c] = zcol[(size_t)c * 65536 + nb + pt];
  }
  __syncthreads();
  const int p = tid >> 2, q = tid & 3;       // row, quarter (8 floats)
  float v[8];
#pragma unroll
  for (int k = 0; k < 8; ++k) v[k] = tile[p][q * 8 + k];
  float* op = zrow + (size_t)(nb + p) * 32 + q * 8;
  f32x4 lo = {v[0], v[1], v[2], v[3]};
  f32x4 hi = {v[4], v[5], v[6], v[7]};
  *(f32x4*)op = lo;
  *(f32x4*)(op + 4) = hi;
  bf16x8 bv;
#pragma unroll
  for (int k = 0; k < 8; ++k) bv[k] = f2bf(-v[k]);
  *(bf16x8*)(zrowb + (size_t)(nb + p) * 32 + q * 8) = bv;
}

// -- final scale (pn=16): out = (z - f_rest) + embed[idx], idx out, loss --
__global__ __launch_bounds__(256) void final_add_kernel(
    const float* __restrict__ z, const float* __restrict__ f_rest,
    const float* __restrict__ embed, const unsigned long long* __restrict__ keys,
    float* __restrict__ f_hat, float* __restrict__ idx_out,
    float* __restrict__ loss_slot)
{
  const int tid = threadIdx.x;
  const int t = blockIdx.x * 256 + tid;
  const int c = blockIdx.x & 31, b = blockIdx.x >> 5;
  const int n = b * 256 + tid;
  int idx = keyidx(keys[n]);
  if (c == 0) idx_out[n] = (float)idx;
  float e = embed[(size_t)idx * 32 + c];
  float fr = f_rest[t];
  f_hat[t] = (z[t] - fr) + e;   // f_hat = sum of zq (err ~1e-6)
  float d = e - fr;             // fr == zavg at pn=16 bit-exactly
  float lsum = d * d;
#pragma unroll
  for (int off = 32; off > 0; off >>= 1) lsum += __shfl_down(lsum, off, 64);
  if ((tid & 63) == 0)
    atomicAdd(loss_slot + ((blockIdx.x & 127) << 4), lsum);
}

// ------------- final loss reduce: 5 scales x 128 padded slots -------------
__global__ __launch_bounds__(128) void loss_final_kernel(
    const float* __restrict__ loss_slots, float* __restrict__ out_loss)
{
  __shared__ float lred[2];
  const int tid = threadIdx.x;   // 128 threads = 2 waves
  const float numel[5] = {8192.f, 32768.f, 131072.f, 524288.f, 2097152.f};
  float tot = 0.f;
  for (int s = 0; s < 5; ++s) {
    float x = loss_slots[s * 2048 + tid * 16];
#pragma unroll
    for (int off = 32; off > 0; off >>= 1) x += __shfl_down(x, off, 64);
    if ((tid & 63) == 0) lred[tid >> 6] = x;
    __syncthreads();
    if (tid == 0) {
      float m = (lred[0] + lred[1]) / numel[s];
      tot += 0.25f * m + m;        // beta*mean + mean
    }
    __syncthreads();
  }
  if (tid == 0) out_loss[0] = tot / 5.f;
}

// =========================== host launcher ===========================
extern "C" void kernel_launch(void* const* d_in, const int* in_sizes, int n_in,
                              void* d_out, int out_size, void* d_ws, size_t ws_size,
                              hipStream_t stream)
{
  const float* z     = (const float*)d_in[0];
  const float* embed = (const float*)d_in[1];
  float* out = (float*)d_out;
  float* ws  = (float*)d_ws;

  // ws layout (float slots), total 5569024 floats ~= 21.2 MiB
  float* f_rest  = ws;                                   // 2097152
  float* zrow    = ws + 2097152;                         // [65536][32] f32
  short* zrowb   = (short*)(ws + 4194304);               // [65536][32] bf16(-z)
  short* ebf     = (short*)(ws + 5242880);               // 131072 shorts
  float* se      = ws + 5308416;                         // 4096
  unsigned int* smin0 = (unsigned int*)(ws + 5312512);   // 65536 u32
  unsigned int* smin1 = (unsigned int*)(ws + 5378048);   // 16384 u32
  unsigned long long* keys0 = (unsigned long long*)(ws + 5394432); // 65536 u64
  unsigned long long* keys1 = (unsigned long long*)(ws + 5525504); // 16384 u64
  float* loss_slots = ws + 5558272;                      // 5*128*16 = 10240
  float* tables     = ws + 5568512;                      // 512

  // zcol scratch = f_hat region of d_out (32 x 65536 f32 exactly);
  // final_add overwrites it at the end.
  float* zcol = out;

  unsigned long long* keysb[2] = {keys0, keys1};
  unsigned int*       sminb[2] = {smin0, smin1};

  setup_kernel<<<NTOT / 256, 256, 0, stream>>>(z, embed, f_rest, zrow, zrowb,
                                               ebf, se, tables, loss_slots,
                                               keys0, smin0);

  const int PN[5]  = {1, 2, 4, 8, 16};
  const int NVC[5] = {32, 32, 32, 16, 16};  // v-chunks; vchunk multiple of WIN
  int idx_off = NTOT;
  for (int i = 0; i < 5; ++i) {
    int pn = PN[i];
    int N  = B_ * pn * pn;
    int vchunk = V_ / NVC[i];
    unsigned long long* kb = keysb[i & 1];
    unsigned int*       sb = sminb[i & 1];
    dim3 g(N / 128, NVC[i]);                  // 2-frag waves: 128 points/block
    vq_phaseA_kernel<<<g, 256, 0, stream>>>(zrowb, ebf, se, sb, vchunk);
    vq_phaseB_kernel<<<g, 256, 0, stream>>>(zrowb, ebf, se, sb, zrow, embed,
                                            kb, vchunk, N);
    if (i < 4) {
      int pnn = PN[i + 1];
      int n_next = B_ * pnn * pnn;
      up_update_kernel<<<NTOT / 256, 256, 0, stream>>>(
          embed, kb, tables + i * 128, f_rest, pn,
          zcol, keysb[(i + 1) & 1], sminb[(i + 1) & 1],
          pnn, n_next, out + idx_off, loss_slots + i * 2048);
      zpack_transpose_kernel<<<n_next / 64, 256, 0, stream>>>(zcol, zrow,
                                                              zrowb);
    } else {
      final_add_kernel<<<NTOT / 256, 256, 0, stream>>>(
          z, f_rest, embed, kb, out, out + idx_off, loss_slots + 4 * 2048);
    }
    idx_off += N;
  }
  loss_final_kernel<<<1, 128, 0, stream>>>(loss_slots, out + 2184448);
}